// Round 1
// baseline (113.372 us; speedup 1.0000x reference)
//
#include <hip/hip_runtime.h>

// Depthwise causal conv1d with learnable hidden-state prefix.
// x: [B, D, L] f32; weight: [D,1,4] f32; bias: [D] f32; init_state: [D,3] f32
// out: [B, D, L+3] f32
//
// out[b,d,t] = bias[d] + sum_{j=0..3} w[d,j] * xm(t-3+j)
//   xm(i) = init_state[d, i+3]  for -3 <= i < 0
//         = x[b,d,i]            for 0 <= i < L
//         = 0                   for i >= L

namespace {

constexpr int B = 4;
constexpr int D = 4096;
constexpr int L = 4096;
constexpr int LOUT = L + 3;          // 4099
constexpr int CHUNKS = L / 4 + 1;    // 1024 vec4 chunks + 1 tail chunk = 1025
constexpr unsigned ROWS = B * D;     // 16384

__global__ __launch_bounds__(256) void causal_conv1d_kernel(
    const float* __restrict__ x,
    const float* __restrict__ w,      // [D,4]
    const float* __restrict__ bias,   // [D]
    const float* __restrict__ init,   // [D,3]
    float* __restrict__ out)
{
    unsigned idx = blockIdx.x * 256u + threadIdx.x;
    unsigned row = idx / CHUNKS;          // magic-mul division
    unsigned tr  = idx - row * CHUNKS;
    if (row >= ROWS) return;

    unsigned d = row & (D - 1);
    const float* xr = x + (size_t)row * L;
    float* outr = out + (size_t)row * LOUT;

    // weights broadcast across the row's threads (same address per wave -> 1 txn)
    float w0 = w[d * 4 + 0];
    float w1 = w[d * 4 + 1];
    float w2 = w[d * 4 + 2];
    float w3 = w[d * 4 + 3];
    float b  = bias[d];

    if (tr < (unsigned)(L / 4)) {
        int t0 = (int)tr * 4;
        float4 cur = *reinterpret_cast<const float4*>(xr + t0);   // x[t0..t0+3], 16B aligned
        float pm3, pm2, pm1;                                      // xm(t0-3..t0-1)
        if (t0 == 0) {
            pm3 = init[d * 3 + 0];
            pm2 = init[d * 3 + 1];
            pm1 = init[d * 3 + 2];
        } else {
            float4 prev = *reinterpret_cast<const float4*>(xr + t0 - 4);  // x[t0-4..t0-1]
            pm3 = prev.y; pm2 = prev.z; pm1 = prev.w;
        }
        float o0 = b + w0 * pm3   + w1 * pm2   + w2 * pm1   + w3 * cur.x;
        float o1 = b + w0 * pm2   + w1 * pm1   + w2 * cur.x + w3 * cur.y;
        float o2 = b + w0 * pm1   + w1 * cur.x + w2 * cur.y + w3 * cur.z;
        float o3 = b + w0 * cur.x + w1 * cur.y + w2 * cur.z + w3 * cur.w;
        outr[t0 + 0] = o0;
        outr[t0 + 1] = o1;
        outr[t0 + 2] = o2;
        outr[t0 + 3] = o3;
    } else {
        // tail: t = L..L+2, window runs past the end (zeros)
        float xa = xr[L - 3], xb = xr[L - 2], xc = xr[L - 1];
        outr[L + 0] = b + w0 * xa + w1 * xb + w2 * xc;  // t=4096
        outr[L + 1] = b + w0 * xb + w1 * xc;            // t=4097
        outr[L + 2] = b + w0 * xc;                      // t=4098
    }
}

} // namespace

extern "C" void kernel_launch(void* const* d_in, const int* in_sizes, int n_in,
                              void* d_out, int out_size, void* d_ws, size_t ws_size,
                              hipStream_t stream) {
    const float* x    = (const float*)d_in[0];  // [B,D,L]
    const float* w    = (const float*)d_in[1];  // [D,1,4]
    const float* bias = (const float*)d_in[2];  // [D]
    const float* init = (const float*)d_in[3];  // [D,3]
    float* out = (float*)d_out;                 // [B,D,L+3]

    unsigned total = ROWS * (unsigned)CHUNKS;   // 16384 * 1025 = 16,793,600
    unsigned blocks = (total + 255u) / 256u;    // 65,600
    causal_conv1d_kernel<<<blocks, 256, 0, stream>>>(x, w, bias, init, out);
}

// Round 2
// 102.607 us; speedup vs baseline: 1.1049x; 1.1049x over previous
//
#include <hip/hip_runtime.h>

// Depthwise causal conv1d with learnable hidden-state prefix.
// x: [B, D, L] f32; weight: [D,1,4] f32; bias: [D] f32; init_state: [D,3] f32
// out: [B, D, L+3] f32
//
// out[b,d,t] = bias[d] + sum_{j=0..3} w[d,j] * xm(t-3+j)
//   xm(i) = init_state[d, i+3]  for -3 <= i < 0
//         = x[b,d,i]            for 0 <= i < L
//         = 0                   for i >= L
//
// Lane-dense mapping: each store/load instruction is wave-contiguous
// (lane i handles output t = base + i), eliminating the 4x strided-store
// request amplification of the previous version.

namespace {

constexpr int D = 4096;
constexpr int L = 4096;
constexpr int LOUT = L + 3;   // 4099
// 4 blocks per row, each covering 1024 outputs (256 thr x 4 iters);
// block with seg==3 also handles the 3-element tail t in [4096, 4099).

__global__ __launch_bounds__(256) void causal_conv1d_kernel(
    const float* __restrict__ x,
    const float* __restrict__ w,      // [D,4]
    const float* __restrict__ bias,   // [D]
    const float* __restrict__ init,   // [D,3]
    float* __restrict__ out)
{
    unsigned bid = blockIdx.x;
    unsigned row = bid >> 2;          // 4 segments per row
    unsigned seg = bid & 3u;
    unsigned d   = row & (D - 1);

    const float* xr  = x + (size_t)row * L;
    float*       outr = out + (size_t)row * LOUT;

    // block-uniform -> scalar loads
    float w0 = w[d * 4 + 0];
    float w1 = w[d * 4 + 1];
    float w2 = w[d * 4 + 2];
    float w3 = w[d * 4 + 3];
    float b  = bias[d];

    unsigned tb = seg * 1024u + threadIdx.x;

#pragma unroll
    for (int k = 0; k < 4; ++k) {
        int t = (int)tb + k * 256;    // t <= 4095 always here
        float v0, v1, v2, v3;
        if (t >= 3) {
            // interior fast path: 4 dense dword loads, lines shared via L1
            v0 = xr[t - 3];
            v1 = xr[t - 2];
            v2 = xr[t - 1];
            v3 = xr[t];
        } else {
            // t in {0,1,2}: splice learnable state (3 lanes of one wave total)
            v0 = init[d * 3 + t];                            // idx t-3 -> init[t]
            v1 = (t - 2 >= 0) ? xr[t - 2] : init[d * 3 + t + 1];
            v2 = (t - 1 >= 0) ? xr[t - 1] : init[d * 3 + t + 2];
            v3 = xr[t];
        }
        outr[t] = b + w0 * v0 + w1 * v1 + w2 * v2 + w3 * v3;
    }

    // tail: t = 4096..4098, window runs past end of x (zeros)
    if (seg == 3u && threadIdx.x < 3u) {
        int t  = L + (int)threadIdx.x;
        int i0 = t - 3;               // 4093..4095, always valid
        float acc = b + w0 * xr[i0];
        if (i0 + 1 < L) acc += w1 * xr[i0 + 1];
        if (i0 + 2 < L) acc += w2 * xr[i0 + 2];
        outr[t] = acc;
    }
}

} // namespace

extern "C" void kernel_launch(void* const* d_in, const int* in_sizes, int n_in,
                              void* d_out, int out_size, void* d_ws, size_t ws_size,
                              hipStream_t stream) {
    const float* x    = (const float*)d_in[0];  // [B,D,L]
    const float* w    = (const float*)d_in[1];  // [D,1,4]
    const float* bias = (const float*)d_in[2];  // [D]
    const float* init = (const float*)d_in[3];  // [D,3]
    float* out = (float*)d_out;                 // [B,D,L+3]

    unsigned rows = (unsigned)(in_sizes[0] / L);   // B*D = 16384
    unsigned blocks = rows * 4u;                   // 65536
    causal_conv1d_kernel<<<blocks, 256, 0, stream>>>(x, w, bias, init, out);
}